// Round 1
// baseline (4272.028 us; speedup 1.0000x reference)
//
#include <hip/hip_runtime.h>
#include <math.h>

#define Vv 32000
#define Ee 256
#define Hh 512
#define Bb 64
#define Ss 64

typedef __attribute__((ext_vector_type(8))) short bf16x8;
typedef __attribute__((ext_vector_type(4))) float f32x4;

__device__ __forceinline__ short f2bf(float x) {
  unsigned u = __float_as_uint(x);
  u = u + 0x7FFFu + ((u >> 16) & 1u);
  return (short)(u >> 16);
}
__device__ __forceinline__ float sigm(float x) { return 1.f / (1.f + expf(-x)); }

// ---------------- prep 1: fc_w fp32 -> bf16, B-fragment swizzled ----------------
// layout: [vtile(2000)][kk(16)][q(4)][n(16)][j(8)], element (v=vtile*16+n, k=kk*32+q*8+j)
__global__ __launch_bounds__(256) void k_prep_fcw(const float* __restrict__ fcw,
                                                  short* __restrict__ fcw_frag) {
  int dst = blockIdx.x * 256 + threadIdx.x;
  if (dst >= Vv * Hh) return;
  int j = dst & 7;
  int n = (dst >> 3) & 15;
  int q = (dst >> 7) & 3;
  int kk = (dst >> 9) & 15;
  int vt = dst >> 13;
  int v = vt * 16 + n;
  int k = kk * 32 + q * 8 + j;
  fcw_frag[dst] = f2bf(fcw[v * Hh + k]);
}

// ---------------- prep 2: misc init ----------------
__global__ __launch_bounds__(256) void k_prep_misc(const float* __restrict__ h0,
                                                   const int* __restrict__ captions,
                                                   const float* __restrict__ emb,
                                                   const float* __restrict__ bih,
                                                   const float* __restrict__ bhh,
                                                   float* __restrict__ out,
                                                   float* __restrict__ hT4a,
                                                   float* __restrict__ cT,
                                                   float* __restrict__ xT4,
                                                   float* __restrict__ bsum) {
  int i = blockIdx.x * 256 + threadIdx.x;  // 8000*256 = 2,048,000
  if (i < Bb * Vv) {                       // zero out[:,0,:]
    int b = i / Vv;
    int v = i - b * Vv;
    out[b * (Ss * Vv) + v] = 0.f;
  }
  if (i < Bb * Hh) {  // hT4 (k-major float groups of 4) + cT zero
    int b = i & 63;
    int k = i >> 6;
    hT4a[(k >> 2) * 256 + b * 4 + (k & 3)] = h0[b * Hh + k];
    cT[i] = 0.f;
  }
  if (i < Bb * Ee) {  // xT4 from tok0 = captions[:,0]
    int b = i & 63;
    int k = i >> 6;
    int t0 = captions[b * Ss];
    xT4[(k >> 2) * 256 + b * 4 + (k & 3)] = (t0 == 0) ? 0.f : emb[t0 * Ee + k];
  }
  if (i < 4 * Hh) bsum[i] = bih[i] + bhh[i];
}

// ---------------- gates + cell (fp32 exact) ----------------
// 256 blocks * 256 thr; block owns units u0,u0+1. Waves split K; partials reduced in LDS.
__global__ __launch_bounds__(256) void k_gates(const float* __restrict__ xT4,
                                               const float* __restrict__ hT4_in,
                                               float* __restrict__ hT4_out,
                                               float* __restrict__ h_row,
                                               short* __restrict__ hfrag,
                                               float* __restrict__ cT,
                                               const float* __restrict__ Wih,
                                               const float* __restrict__ Whh,
                                               const float* __restrict__ bsum) {
  __shared__ float sgp[2048];  // [w][g][ul][b]
  int tid = threadIdx.x;
  int b = tid & 63;
  int w = tid >> 6;
  int u0 = blockIdx.x * 2;

  float acc[4][2];
#pragma unroll
  for (int g = 0; g < 4; g++) {
    acc[g][0] = 0.f;
    acc[g][1] = 0.f;
  }

  // x-part: K=256 -> k4 in [w*16, w*16+16)
  {
    const float4* A0 = (const float4*)xT4;
    for (int k4 = w * 16; k4 < w * 16 + 16; k4++) {
      float4 a = A0[k4 * 64 + b];
#pragma unroll
      for (int g = 0; g < 4; g++) {
#pragma unroll
        for (int u = 0; u < 2; u++) {
          float4 wv = ((const float4*)(Wih + (size_t)(g * Hh + u0 + u) * Ee))[k4];
          acc[g][u] += a.x * wv.x + a.y * wv.y + a.z * wv.z + a.w * wv.w;
        }
      }
    }
  }
  // h-part: K=512 -> k4 in [w*32, w*32+32)
  {
    const float4* A1 = (const float4*)hT4_in;
    for (int k4 = w * 32; k4 < w * 32 + 32; k4++) {
      float4 a = A1[k4 * 64 + b];
#pragma unroll
      for (int g = 0; g < 4; g++) {
#pragma unroll
        for (int u = 0; u < 2; u++) {
          float4 wv = ((const float4*)(Whh + (size_t)(g * Hh + u0 + u) * Hh))[k4];
          acc[g][u] += a.x * wv.x + a.y * wv.y + a.z * wv.z + a.w * wv.w;
        }
      }
    }
  }
#pragma unroll
  for (int g = 0; g < 4; g++)
#pragma unroll
    for (int u = 0; u < 2; u++) sgp[((w * 4 + g) * 2 + u) * 64 + b] = acc[g][u];
  __syncthreads();

  if (tid < 128) {
    int bb = tid & 63;
    int ul = tid >> 6;
    int u = u0 + ul;
    float s[4];
#pragma unroll
    for (int g = 0; g < 4; g++) {
      s[g] = sgp[((0 * 4 + g) * 2 + ul) * 64 + bb] + sgp[((1 * 4 + g) * 2 + ul) * 64 + bb] +
             sgp[((2 * 4 + g) * 2 + ul) * 64 + bb] + sgp[((3 * 4 + g) * 2 + ul) * 64 + bb];
    }
    float gi = s[0] + bsum[u];
    float gf = s[1] + bsum[Hh + u];
    float gg = s[2] + bsum[2 * Hh + u];
    float go = s[3] + bsum[3 * Hh + u];
    float c = sigm(gf) * cT[u * 64 + bb] + sigm(gi) * tanhf(gg);
    cT[u * 64 + bb] = c;
    float h = sigm(go) * tanhf(c);
    hT4_out[(u >> 2) * 256 + bb * 4 + (u & 3)] = h;
    h_row[bb * Hh + u] = h;
    int kk = u >> 5, q = (u >> 3) & 3, j = u & 7;
    hfrag[((kk * 4 + q) * 64 + bb) * 8 + j] = f2bf(h);
  }
}

// ---------------- FC logits GEMM (bf16 MFMA), M=64 N=32000 K=512 ----------------
// 250 blocks * 256 thr (4 waves). wave: n-slice of 32, m=64. A staged in LDS (frag order).
__global__ __launch_bounds__(256) void k_gemm(const short* __restrict__ hfrag,
                                              const short* __restrict__ fcw_frag,
                                              const float* __restrict__ fcb,
                                              float* __restrict__ out, int t) {
  __shared__ __align__(16) short lds_h[32768];  // 64 KB
  int tid = threadIdx.x;
  {
    const float4* s = (const float4*)hfrag;
    float4* d = (float4*)lds_h;
    for (int i = tid; i < 4096; i += 256) d[i] = s[i];
  }
  __syncthreads();

  int lane = tid & 63;
  int w = tid >> 6;
  int nbase = blockIdx.x * 128 + w * 32;
  int n = lane & 15;  // also m for A-frags
  int q = lane >> 4;
  int vt0 = nbase >> 4;

  f32x4 acc[4][2];
#pragma unroll
  for (int mt = 0; mt < 4; mt++)
#pragma unroll
    for (int nt = 0; nt < 2; nt++) acc[mt][nt] = (f32x4){0.f, 0.f, 0.f, 0.f};

  const bf16x8* Bp = (const bf16x8*)fcw_frag;
  for (int kk = 0; kk < 16; kk++) {
    int abase = (kk * 4 + q) * 64;
    bf16x8 a0 = *(const bf16x8*)(lds_h + (abase + 0 + n) * 8);
    bf16x8 a1 = *(const bf16x8*)(lds_h + (abase + 16 + n) * 8);
    bf16x8 a2 = *(const bf16x8*)(lds_h + (abase + 32 + n) * 8);
    bf16x8 a3 = *(const bf16x8*)(lds_h + (abase + 48 + n) * 8);
    bf16x8 b0 = Bp[(size_t)vt0 * 1024 + (kk * 4 + q) * 16 + n];
    bf16x8 b1 = Bp[(size_t)(vt0 + 1) * 1024 + (kk * 4 + q) * 16 + n];
    acc[0][0] = __builtin_amdgcn_mfma_f32_16x16x32_bf16(a0, b0, acc[0][0], 0, 0, 0);
    acc[1][0] = __builtin_amdgcn_mfma_f32_16x16x32_bf16(a1, b0, acc[1][0], 0, 0, 0);
    acc[2][0] = __builtin_amdgcn_mfma_f32_16x16x32_bf16(a2, b0, acc[2][0], 0, 0, 0);
    acc[3][0] = __builtin_amdgcn_mfma_f32_16x16x32_bf16(a3, b0, acc[3][0], 0, 0, 0);
    acc[0][1] = __builtin_amdgcn_mfma_f32_16x16x32_bf16(a0, b1, acc[0][1], 0, 0, 0);
    acc[1][1] = __builtin_amdgcn_mfma_f32_16x16x32_bf16(a1, b1, acc[1][1], 0, 0, 0);
    acc[2][1] = __builtin_amdgcn_mfma_f32_16x16x32_bf16(a2, b1, acc[2][1], 0, 0, 0);
    acc[3][1] = __builtin_amdgcn_mfma_f32_16x16x32_bf16(a3, b1, acc[3][1], 0, 0, 0);
  }

  // C layout: col = lane&15 (n), row(m) = (lane>>4)*4 + reg
  float fb0 = fcb[nbase + n];
  float fb1 = fcb[nbase + 16 + n];
#pragma unroll
  for (int mt = 0; mt < 4; mt++) {
#pragma unroll
    for (int r = 0; r < 4; r++) {
      int b = mt * 16 + q * 4 + r;
      float* o = out + (size_t)(b * Ss + t) * Vv + nbase;
      o[n] = acc[mt][0][r] + fb0;
      o[16 + n] = acc[mt][1][r] + fb1;
    }
  }
}

// ---------------- argmax + fp32 refine + token select + embed gather ----------------
__global__ __launch_bounds__(256) void k_sel(const float* __restrict__ out,
                                             const float* __restrict__ h_row,
                                             const float* __restrict__ fcw,
                                             const float* __restrict__ fcb,
                                             const int* __restrict__ captions,
                                             const int* __restrict__ use_tf,
                                             const float* __restrict__ emb,
                                             float* __restrict__ xT4, int t) {
  __shared__ float sval[256];
  __shared__ int sidx[256];
  __shared__ int cand[128];
  __shared__ float cref[128];
  __shared__ int cnt;
  __shared__ int stok;
  int tid = threadIdx.x;
  int b = blockIdx.x;
  const float* row = out + (size_t)(b * Ss + t) * Vv;
  const float4* r4 = (const float4*)row;

  float best = -1e30f;
  int bestv = 0;
  for (int i = tid; i < Vv / 4; i += 256) {
    float4 x = r4[i];
    int v = i * 4;
    if (x.x > best) { best = x.x; bestv = v; }
    if (x.y > best) { best = x.y; bestv = v + 1; }
    if (x.z > best) { best = x.z; bestv = v + 2; }
    if (x.w > best) { best = x.w; bestv = v + 3; }
  }
  sval[tid] = best;
  sidx[tid] = bestv;
  __syncthreads();
  for (int s = 128; s; s >>= 1) {
    if (tid < s) {
      float ov = sval[tid + s];
      int oi = sidx[tid + s];
      if (ov > sval[tid] || (ov == sval[tid] && oi < sidx[tid])) {
        sval[tid] = ov;
        sidx[tid] = oi;
      }
    }
    __syncthreads();
  }
  float thr = sval[0] - 0.0625f;
  if (tid == 0) cnt = 0;
  __syncthreads();
  for (int i = tid; i < Vv / 4; i += 256) {
    float4 x = r4[i];
    int v = i * 4;
    if (x.x >= thr) { int p = atomicAdd(&cnt, 1); if (p < 128) cand[p] = v; }
    if (x.y >= thr) { int p = atomicAdd(&cnt, 1); if (p < 128) cand[p] = v + 1; }
    if (x.z >= thr) { int p = atomicAdd(&cnt, 1); if (p < 128) cand[p] = v + 2; }
    if (x.w >= thr) { int p = atomicAdd(&cnt, 1); if (p < 128) cand[p] = v + 3; }
  }
  __syncthreads();
  int nc = cnt < 128 ? cnt : 128;
  int lane = tid & 63;
  int w = tid >> 6;
  const float4* hv = (const float4*)(h_row + b * Hh);
  for (int ci = w; ci < nc; ci += 4) {
    int v = cand[ci];
    const float4* wv = (const float4*)(fcw + (size_t)v * Hh);
    float4 a0 = hv[lane * 2], a1 = hv[lane * 2 + 1];
    float4 w0 = wv[lane * 2], w1 = wv[lane * 2 + 1];
    float s = a0.x * w0.x + a0.y * w0.y + a0.z * w0.z + a0.w * w0.w + a1.x * w1.x +
              a1.y * w1.y + a1.z * w1.z + a1.w * w1.w;
    for (int off = 32; off; off >>= 1) s += __shfl_xor(s, off);
    if (lane == 0) cref[ci] = s + fcb[v];
  }
  __syncthreads();
  if (tid == 0) {
    float bv = -1e30f;
    int bi = 0x7fffffff;
    for (int ci = 0; ci < nc; ci++) {
      float rv = cref[ci];
      int v = cand[ci];
      if (rv > bv || (rv == bv && v < bi)) { bv = rv; bi = v; }
    }
    stok = use_tf[t] ? captions[b * Ss + t] : bi;
  }
  __syncthreads();
  int tok = stok;
  {
    int k = tid;  // 256 threads == E
    float val = (tok == 0) ? 0.f : emb[(size_t)tok * Ee + k];
    xT4[(k >> 2) * 256 + b * 4 + (k & 3)] = val;
  }
}

extern "C" void kernel_launch(void* const* d_in, const int* in_sizes, int n_in,
                              void* d_out, int out_size, void* d_ws, size_t ws_size,
                              hipStream_t stream) {
  const float* h0 = (const float*)d_in[0];
  const int* captions = (const int*)d_in[1];
  const int* use_tf = (const int*)d_in[2];
  const float* emb = (const float*)d_in[3];
  const float* Wih = (const float*)d_in[4];
  const float* Whh = (const float*)d_in[5];
  const float* bih = (const float*)d_in[6];
  const float* bhh = (const float*)d_in[7];
  const float* fcw = (const float*)d_in[8];
  const float* fcb = (const float*)d_in[9];
  float* out = (float*)d_out;

  char* ws = (char*)d_ws;
  short* fcw_frag = (short*)(ws);                  // 32,768,000 B
  short* hfrag = (short*)(ws + 32768000);          //     65,536 B
  float* hT4a = (float*)(ws + 32833536);           //    131,072 B
  float* hT4b = (float*)(ws + 32964608);           //    131,072 B
  float* h_row = (float*)(ws + 33095680);          //    131,072 B
  float* cT = (float*)(ws + 33226752);             //    131,072 B
  float* xT4 = (float*)(ws + 33357824);            //     65,536 B
  float* bsum = (float*)(ws + 33423360);           //      8,192 B

  k_prep_fcw<<<64000, 256, 0, stream>>>(fcw, fcw_frag);
  k_prep_misc<<<8000, 256, 0, stream>>>(h0, captions, emb, bih, bhh, out, hT4a, cT, xT4,
                                        bsum);

  for (int t = 1; t <= 63; t++) {
    const float* hin = (t & 1) ? hT4a : hT4b;  // prep wrote hT4a; gates(1) writes hT4b
    float* hout = (t & 1) ? hT4b : hT4a;
    k_gates<<<256, 256, 0, stream>>>(xT4, hin, hout, h_row, hfrag, cT, Wih, Whh, bsum);
    k_gemm<<<250, 256, 0, stream>>>(hfrag, fcw_frag, fcb, out, t);
    if (t < 63)
      k_sel<<<64, 256, 0, stream>>>(out, h_row, fcw, fcb, captions, use_tf, emb, xT4, t);
  }
}